// Round 18
// baseline (114.556 us; speedup 1.0000x reference)
//
#include <hip/hip_runtime.h>
#include <hip/hip_fp16.h>
#include <math.h>

// Elastic transform: [32,256,1024,3] fp32, 3x3 control grid displacement.
//   k_wfilt  : spline prefilter along W (17-tap mirror FIR, f32 math), x ->
//              48 PAIR-PLANES: dword = fp16 pair (batch p, batch p+16)
//   k_hfilt  : prefilter along H in place, 13-tap, PACKED-f16 math
//   k_sample : displacement computed in-register (scalarized), then 4x4
//              cubic gather; __launch_bounds__(256,1) lifts the register
//              budget (R16/R17 spilled ~104 MB scratch at VGPR=32).
//
// fp16 storage; pk-f16 math in k_sample x-reduction and hfilt FIR.

#define H_ 256
#define W_ 1024
#define B_ 32
#define RAD 8                // wfilt radius: |z|^9 trunc ~1e-4
#define RADH 6               // hfilt radius: trunc ~2e-3
#define ROWF 3072            // W_*3 floats per (b,h) row of x
#define HW_ (H_ * W_)        // 262144 dwords per pair-plane

typedef float f4a __attribute__((ext_vector_type(4), aligned(4)));
typedef _Float16 h2 __attribute__((ext_vector_type(2)));

__device__ __forceinline__ h2 bch2(float d) { return __builtin_bit_cast(h2, d); }
__device__ __forceinline__ float bcf(h2 v) { return __builtin_bit_cast(float, v); }

__device__ __forceinline__ float b3f(float t) {
    float a = fabsf(t);
    if (a < 1.0f) return (4.0f - 6.0f * a * a + 3.0f * a * a * a) * (1.0f / 6.0f);
    if (a < 2.0f) { float s = 2.0f - a; return s * s * s * (1.0f / 6.0f); }
    return 0.0f;
}

__device__ __forceinline__ void cubw(float f, float* w) {
    float f2 = f * f, f3 = f2 * f;
    float om = 1.0f - f;
    w[0] = om * om * om * (1.0f / 6.0f);
    w[1] = (3.0f * f3 - 6.0f * f2 + 4.0f) * (1.0f / 6.0f);
    w[2] = (-3.0f * f3 + 3.0f * f2 + 3.0f * f + 1.0f) * (1.0f / 6.0f);
    w[3] = f3 * (1.0f / 6.0f);
}

__device__ __forceinline__ float clamp01(float v) {
    return fminf(fmaxf(v, 0.0f), 1.0f);
}

__device__ __forceinline__ float2 up2(float d) {
    return __half22float2(__builtin_bit_cast(__half2, d));
}
__device__ __forceinline__ float pk2(float a, float b) {
    return __builtin_bit_cast(float, __floats2half2_rn(a, b));
}

__device__ __forceinline__ void basis3(int i, int n, float& w0, float& w1, float& w2) {
    float u = (float)i * 2.0f / (float)(n - 1);
    int base = (int)floorf(u);
    w0 = w1 = w2 = 0.0f;
#pragma unroll
    for (int k = -1; k < 3; ++k) {
        int id = base + k;
        float bw = b3f(u - (float)id);
        int j = id < 0 ? -id : id;
        j &= 3;
        if (j == 3) j = 1;
        if (j == 0) w0 += bw; else if (j == 1) w1 += bw; else w2 += bw;
    }
}

// ---------------- kernel 1: prefilter along W -> pair-planes --------------
// block bp = p*256 + h handles rows (p,h) AND (p+16,h); f32 math.
#define PLN 1040
__global__ __launch_bounds__(256) void k_wfilt(const float* __restrict__ x,
                                               float* __restrict__ pairP) {
    __shared__ float pl[6 * PLN];
    const int bp = blockIdx.x;           // p*256 + h, p in 0..15
    const int p = bp >> 8, h = bp & 255;
    const int t = threadIdx.x;

#pragma unroll
    for (int bi = 0; bi < 2; ++bi) {
        const float* row = x + ((size_t)(p + 16 * bi) * H_ + h) * ROWF;
        float4 v0 = *(const float4*)(row + 12 * t);
        float4 v1 = *(const float4*)(row + 12 * t + 4);
        float4 v2 = *(const float4*)(row + 12 * t + 8);
        float4 c0, c1, c2;
        c0.x = v0.x; c0.y = v0.w; c0.z = v1.z; c0.w = v2.y;
        c1.x = v0.y; c1.y = v1.x; c1.z = v1.w; c1.w = v2.z;
        c2.x = v0.z; c2.y = v1.y; c2.z = v2.x; c2.w = v2.w;
        *(float4*)(pl + (bi * 3 + 0) * PLN + 8 + 4 * t) = c0;
        *(float4*)(pl + (bi * 3 + 1) * PLN + 8 + 4 * t) = c1;
        *(float4*)(pl + (bi * 3 + 2) * PLN + 8 + 4 * t) = c2;
    }
    __syncthreads();

    if (t < 96) {                        // mirror halos: 6 rows x (8+8)
        int rb = t / 48, rem = t % 48;
        int c = rem >> 4, i = rem & 15;
        float* pp = pl + (rb * 3 + c) * PLN;
        if (i < 8) { int j = i + 1; pp[8 - j] = pp[8 + j]; }
        else { int r = i - 8; pp[1032 + r] = pp[1030 - r]; }
    }
    __syncthreads();

    float g[RAD + 1];
    g[0] = 1.7320508075688773f;
#pragma unroll
    for (int k = 1; k <= RAD; ++k) g[k] = g[k - 1] * (-0.26794919243112270647f);

    float res[2][3][4];
#pragma unroll
    for (int bi = 0; bi < 2; ++bi)
#pragma unroll
        for (int c = 0; c < 3; ++c) {
            const float* pp = pl + (bi * 3 + c) * PLN + 4 * t;
            float w[20];
#pragma unroll
            for (int i = 0; i < 5; ++i) {
                float4 v = *(const float4*)(pp + 4 * i);
                w[4 * i] = v.x; w[4 * i + 1] = v.y;
                w[4 * i + 2] = v.z; w[4 * i + 3] = v.w;
            }
#pragma unroll
            for (int j = 0; j < 4; ++j) {
                float a = g[0] * w[j + 8];
#pragma unroll
                for (int k = 1; k <= 8; ++k)
                    a += g[k] * (w[j + 8 - k] + w[j + 8 + k]);
                res[bi][c][j] = a;
            }
        }

#pragma unroll
    for (int c = 0; c < 3; ++c) {
        float4 o;
        o.x = pk2(res[0][c][0], res[1][c][0]);
        o.y = pk2(res[0][c][1], res[1][c][1]);
        o.z = pk2(res[0][c][2], res[1][c][2]);
        o.w = pk2(res[0][c][3], res[1][c][3]);
        *(float4*)(pairP + (size_t)(p * 3 + c) * HW_ + (size_t)h * W_ + 4 * t) = o;
    }
}

// ---------------- kernel 2: prefilter along H, pk-f16 math ----------------
// grid (32, 48): 48 identical pair-planes. 13-tap, v_pk_fma_f16.
#define TSTR 40
__global__ __launch_bounds__(256) void k_hfilt(float* __restrict__ pairP) {
    __shared__ float tile[H_ * TSTR];   // 40 KiB
    const int t = threadIdx.x;
    float* src = pairP + (size_t)blockIdx.y * HW_ + blockIdx.x * 32;

#pragma unroll
    for (int it = 0; it < 8; ++it) {
        int idx = t + it * 256;          // 0..2047 float4s
        int r = idx >> 3, seg = idx & 7;
        *(float4*)(tile + r * TSTR + seg * 4) =
            *(const float4*)(src + (size_t)r * W_ + seg * 4);
    }
    __syncthreads();

    float g[RADH + 1];
    g[0] = 1.7320508075688773f;
#pragma unroll
    for (int k = 1; k <= RADH; ++k) g[k] = g[k - 1] * (-0.26794919243112270647f);
    h2 gh[RADH + 1];
#pragma unroll
    for (int k = 0; k <= RADH; ++k) gh[k] = bch2(pk2(g[k], g[k]));

    const int cg = t & 7;
    const int prow = t >> 3;
    const int p0 = prow * 8;

    const h2 zz = bch2(0.f);
    h2 acc[8][4];
#pragma unroll
    for (int j = 0; j < 8; ++j)
#pragma unroll
        for (int q = 0; q < 4; ++q) acc[j][q] = zz;

#pragma unroll
    for (int r = 0; r < 8 + 2 * RADH; ++r) {   // 20 rows
        int hh = p0 - RADH + r;
        int m1 = hh < 0 ? -hh : hh;
        int m2 = 2 * (H_ - 1) - hh;
        int mp = m1 < m2 ? m1 : m2;
        float4 v = *(const float4*)(tile + mp * TSTR + cg * 4);
        h2 hv0 = bch2(v.x), hv1 = bch2(v.y), hv2 = bch2(v.z), hv3 = bch2(v.w);
#pragma unroll
        for (int j = 0; j < 8; ++j) {
            const int d = r - RADH - j;
            if (d >= -RADH && d <= RADH) {
                const h2 wgt = gh[d < 0 ? -d : d];
                acc[j][0] += wgt * hv0;
                acc[j][1] += wgt * hv1;
                acc[j][2] += wgt * hv2;
                acc[j][3] += wgt * hv3;
            }
        }
    }

#pragma unroll
    for (int j = 0; j < 8; ++j) {
        float4 o;
        o.x = bcf(acc[j][0]);
        o.y = bcf(acc[j][1]);
        o.z = bcf(acc[j][2]);
        o.w = bcf(acc[j][3]);
        *(float4*)(src + (size_t)(p0 + j) * W_ + cg * 4) = o;
    }
}

// ---------------- kernel 3: displacement (scalarized) + cubic gather ------
// grid (1024, 16): thread owns (h,w) for batches (b0, b0+16).
// __launch_bounds__(256, 1): max register budget — R16/R17 spilled at 32.
__global__ __launch_bounds__(256, 1) void k_sample(const float* __restrict__ pairP,
                                                   const float* __restrict__ disp,
                                                   float* __restrict__ out) {
    __shared__ float os[2][768];
    const int t = threadIdx.x;
    const int hw = blockIdx.x * 256 + t;
    const int b0 = blockIdx.y;            // 0..15; pair (b0, b0+16)
    const int h = hw >> 10, w = hw & 1023;

    // ---- displacement, fully scalarized: dy = (A^T rh)^T D0 (A^T rw) ----
    float rh0, rh1, rh2, rw0, rw1, rw2;
    basis3(h, H_, rh0, rh1, rh2);
    basis3(w, W_, rw0, rw1, rw2);
    const float e0 = 1.75f * rh0 - 0.5f * rh1 + 0.25f * rh2;
    const float e1 = -rh0 + 2.0f * rh1 - rh2;
    const float e2 = 0.25f * rh0 - 0.5f * rh1 + 1.75f * rh2;
    const float f0 = 1.75f * rw0 - 0.5f * rw1 + 0.25f * rw2;
    const float f1 = -rw0 + 2.0f * rw1 - rw2;
    const float f2 = 0.25f * rw0 - 0.5f * rw1 + 1.75f * rw2;
    const float dy = 5.0f * (e0 * (disp[0] * f0 + disp[1] * f1 + disp[2] * f2)
                           + e1 * (disp[3] * f0 + disp[4] * f1 + disp[5] * f2)
                           + e2 * (disp[6] * f0 + disp[7] * f1 + disp[8] * f2));
    const float dx = 5.0f * (e0 * (disp[9]  * f0 + disp[10] * f1 + disp[11] * f2)
                           + e1 * (disp[12] * f0 + disp[13] * f1 + disp[14] * f2)
                           + e2 * (disp[15] * f0 + disp[16] * f1 + disp[17] * f2));

    float cy = (float)h + dy;
    float cx = (float)w + dx;
    float byf = floorf(cy), bxf = floorf(cx);
    int by = (int)byf, bx = (int)bxf;
    float wy[4], wx[4];
    cubw(cy - byf, wy);
    cubw(cx - bxf, wx);

    int iyW[4];
#pragma unroll
    for (int r = 0; r < 4; ++r)
        iyW[r] = min(max(by - 1 + r, 0), H_ - 1) * W_;

    const float* pc0 = pairP + (size_t)(b0 * 3) * HW_;
    const float* pc1 = pc0 + HW_;
    const float* pc2 = pc1 + HW_;

    float sA0 = 0.f, sA1 = 0.f, sA2 = 0.f;
    float sB0 = 0.f, sB1 = 0.f, sB2 = 0.f;

    if (bx >= 1 && bx <= W_ - 3) {
        const h2 w0 = bch2(pk2(wx[0], wx[0]));
        const h2 w1 = bch2(pk2(wx[1], wx[1]));
        const h2 w2 = bch2(pk2(wx[2], wx[2]));
        const h2 w3 = bch2(pk2(wx[3], wx[3]));

#pragma unroll
        for (int r = 0; r < 4; ++r) {
            const int o = iyW[r] + bx - 1;
            f4a v0 = *(const f4a*)(pc0 + o);
            f4a v1 = *(const f4a*)(pc1 + o);
            f4a v2 = *(const f4a*)(pc2 + o);
            const float wyr = wy[r];
            h2 a0 = bch2(v0.x) * w0 + bch2(v0.y) * w1;
            a0 = a0 + bch2(v0.z) * w2 + bch2(v0.w) * w3;
            h2 a1 = bch2(v1.x) * w0 + bch2(v1.y) * w1;
            a1 = a1 + bch2(v1.z) * w2 + bch2(v1.w) * w3;
            h2 a2 = bch2(v2.x) * w0 + bch2(v2.y) * w1;
            a2 = a2 + bch2(v2.z) * w2 + bch2(v2.w) * w3;
            float2 u0 = up2(bcf(a0));
            float2 u1 = up2(bcf(a1));
            float2 u2 = up2(bcf(a2));
            sA0 = fmaf(wyr, u0.x, sA0); sB0 = fmaf(wyr, u0.y, sB0);
            sA1 = fmaf(wyr, u1.x, sA1); sB1 = fmaf(wyr, u1.y, sB1);
            sA2 = fmaf(wyr, u2.x, sA2); sB2 = fmaf(wyr, u2.y, sB2);
        }
    } else {
        int ix4[4];
#pragma unroll
        for (int k = 0; k < 4; ++k) ix4[k] = min(max(bx - 1 + k, 0), W_ - 1);
#pragma unroll
        for (int r = 0; r < 4; ++r) {
            float wyr = wy[r];
#pragma unroll
            for (int k = 0; k < 4; ++k) {
                float wk = wyr * wx[k];
                int o = iyW[r] + ix4[k];
                float2 u0 = up2(pc0[o]);
                float2 u1 = up2(pc1[o]);
                float2 u2 = up2(pc2[o]);
                sA0 += wk * u0.x; sB0 += wk * u0.y;
                sA1 += wk * u1.x; sB1 += wk * u1.y;
                sA2 += wk * u2.x; sB2 += wk * u2.y;
            }
        }
    }

    os[0][3 * t + 0] = clamp01(sA0);
    os[0][3 * t + 1] = clamp01(sA1);
    os[0][3 * t + 2] = clamp01(sA2);
    os[1][3 * t + 0] = clamp01(sB0);
    os[1][3 * t + 1] = clamp01(sB1);
    os[1][3 * t + 2] = clamp01(sB2);
    __syncthreads();

    if (t < 192) {
        float4 vA = *(const float4*)(&os[0][0] + 4 * t);
        float4 vB = *(const float4*)(&os[1][0] + 4 * t);
        float* oA = out + ((size_t)b0 * HW_ + (size_t)blockIdx.x * 256) * 3;
        float* oB = out + ((size_t)(b0 + 16) * HW_ + (size_t)blockIdx.x * 256) * 3;
        *(float4*)(oA + 4 * t) = vA;
        *(float4*)(oB + 4 * t) = vB;
    }
}

extern "C" void kernel_launch(void* const* d_in, const int* in_sizes, int n_in,
                              void* d_out, int out_size, void* d_ws, size_t ws_size,
                              hipStream_t stream) {
    const float* x = (const float*)d_in[0];      // [32,256,1024,3]
    const float* disp = (const float*)d_in[1];   // [2,3,3]
    float* out = (float*)d_out;

    float* pairP = (float*)d_ws;                 // 48 MiB: 48 pair-planes

    k_wfilt<<<dim3((B_ / 2) * H_), dim3(256), 0, stream>>>(x, pairP);

    k_hfilt<<<dim3(32, 48), dim3(256), 0, stream>>>(pairP);

    k_sample<<<dim3(HW_ / 256, B_ / 2), dim3(256), 0, stream>>>(pairP, disp, out);
}

// Round 19
// 95.815 us; speedup vs baseline: 1.1956x; 1.1956x over previous
//
#include <hip/hip_runtime.h>
#include <hip/hip_fp16.h>
#include <math.h>

// Elastic transform: [32,256,1024,3] fp32, 3x3 control grid displacement.
// R19 = exact revert to R15 (verified 96.4 us) — the k_disp fold (R16-R18)
// consistently produced ~106 MB scratch-write traffic and is abandoned.
//   k_disp   : dense (dy,dx) float2 field [256,1024] from 3x3 control points
//   k_wfilt  : spline prefilter along W (17-tap mirror FIR, f32 math), x ->
//              48 PAIR-PLANES: dword = fp16 pair (batch p, batch p+16)
//   k_hfilt  : prefilter along H in place, 13-tap, PACKED-f16 math
//   k_sample : 4x4 cubic gather; thread -> (h,w) x batch-pair (b, b+16);
//              3 dwordx4 tap loads/row serve BOTH batches; pk-f16 x-reduce

#define H_ 256
#define W_ 1024
#define B_ 32
#define RAD 8                // wfilt radius: |z|^9 trunc ~1e-4
#define RADH 6               // hfilt radius: trunc ~2e-3
#define ROWF 3072            // W_*3 floats per (b,h) row of x
#define HW_ (H_ * W_)        // 262144 dwords per pair-plane

typedef float f4a __attribute__((ext_vector_type(4), aligned(4)));
typedef _Float16 h2 __attribute__((ext_vector_type(2)));

__device__ __forceinline__ h2 bch2(float d) { return __builtin_bit_cast(h2, d); }
__device__ __forceinline__ float bcf(h2 v) { return __builtin_bit_cast(float, v); }

__device__ __forceinline__ float b3f(float t) {
    float a = fabsf(t);
    if (a < 1.0f) return (4.0f - 6.0f * a * a + 3.0f * a * a * a) * (1.0f / 6.0f);
    if (a < 2.0f) { float s = 2.0f - a; return s * s * s * (1.0f / 6.0f); }
    return 0.0f;
}

__device__ __forceinline__ void cubw(float f, float* w) {
    float f2 = f * f, f3 = f2 * f;
    float om = 1.0f - f;
    w[0] = om * om * om * (1.0f / 6.0f);
    w[1] = (3.0f * f3 - 6.0f * f2 + 4.0f) * (1.0f / 6.0f);
    w[2] = (-3.0f * f3 + 3.0f * f2 + 3.0f * f + 1.0f) * (1.0f / 6.0f);
    w[3] = f3 * (1.0f / 6.0f);
}

__device__ __forceinline__ float clamp01(float v) {
    return fminf(fmaxf(v, 0.0f), 1.0f);
}

__device__ __forceinline__ float2 up2(float d) {
    return __half22float2(__builtin_bit_cast(__half2, d));
}
__device__ __forceinline__ float pk2(float a, float b) {
    return __builtin_bit_cast(float, __floats2half2_rn(a, b));
}

__device__ __forceinline__ void basis3(int i, int n, float& w0, float& w1, float& w2) {
    float u = (float)i * 2.0f / (float)(n - 1);
    int base = (int)floorf(u);
    w0 = w1 = w2 = 0.0f;
#pragma unroll
    for (int k = -1; k < 3; ++k) {
        int id = base + k;
        float bw = b3f(u - (float)id);
        int j = id < 0 ? -id : id;
        j &= 3;
        if (j == 3) j = 1;
        if (j == 0) w0 += bw; else if (j == 1) w1 += bw; else w2 += bw;
    }
}

// ---------------- kernel 0: displacement field (dy,dx) --------------------
__global__ __launch_bounds__(256) void k_disp(const float* __restrict__ disp,
                                              float2* __restrict__ dxy) {
    int idx = blockIdx.x * 256 + threadIdx.x;
    int h = idx >> 10, w = idx & 1023;

    const float A[3][3] = {{1.75f, -1.0f, 0.25f},
                           {-0.5f,  2.0f, -0.5f},
                           {0.25f, -1.0f, 1.75f}};
    float Ty[3][3], Tx[3][3];
#pragma unroll
    for (int i = 0; i < 3; ++i)
#pragma unroll
        for (int j = 0; j < 3; ++j) {
            float ty = 0.f, tx = 0.f;
#pragma unroll
            for (int k = 0; k < 3; ++k) {
                ty += A[i][k] * (5.0f * disp[k * 3 + j]);
                tx += A[i][k] * (5.0f * disp[9 + k * 3 + j]);
            }
            Ty[i][j] = ty; Tx[i][j] = tx;
        }
    float Cy[3][3], Cx[3][3];
#pragma unroll
    for (int i = 0; i < 3; ++i)
#pragma unroll
        for (int j = 0; j < 3; ++j) {
            float ty = 0.f, tx = 0.f;
#pragma unroll
            for (int k = 0; k < 3; ++k) {
                ty += Ty[i][k] * A[j][k];
                tx += Tx[i][k] * A[j][k];
            }
            Cy[i][j] = ty; Cx[i][j] = tx;
        }

    float rh0, rh1, rh2, rw0, rw1, rw2;
    basis3(h, H_, rh0, rh1, rh2);
    basis3(w, W_, rw0, rw1, rw2);
    float rh[3] = {rh0, rh1, rh2}, rw[3] = {rw0, rw1, rw2};

    float dy = 0.f, dx = 0.f;
#pragma unroll
    for (int i = 0; i < 3; ++i)
#pragma unroll
        for (int j = 0; j < 3; ++j) {
            dy += rh[i] * Cy[i][j] * rw[j];
            dx += rh[i] * Cx[i][j] * rw[j];
        }
    dxy[idx] = make_float2(dy, dx);
}

// ---------------- kernel 1: prefilter along W -> pair-planes --------------
// block bp = p*256 + h handles rows (p,h) AND (p+16,h); f32 math.
#define PLN 1040
__global__ __launch_bounds__(256) void k_wfilt(const float* __restrict__ x,
                                               float* __restrict__ pairP) {
    __shared__ float pl[6 * PLN];
    const int bp = blockIdx.x;           // p*256 + h, p in 0..15
    const int p = bp >> 8, h = bp & 255;
    const int t = threadIdx.x;

#pragma unroll
    for (int bi = 0; bi < 2; ++bi) {
        const float* row = x + ((size_t)(p + 16 * bi) * H_ + h) * ROWF;
        float4 v0 = *(const float4*)(row + 12 * t);
        float4 v1 = *(const float4*)(row + 12 * t + 4);
        float4 v2 = *(const float4*)(row + 12 * t + 8);
        float4 c0, c1, c2;
        c0.x = v0.x; c0.y = v0.w; c0.z = v1.z; c0.w = v2.y;
        c1.x = v0.y; c1.y = v1.x; c1.z = v1.w; c1.w = v2.z;
        c2.x = v0.z; c2.y = v1.y; c2.z = v2.x; c2.w = v2.w;
        *(float4*)(pl + (bi * 3 + 0) * PLN + 8 + 4 * t) = c0;
        *(float4*)(pl + (bi * 3 + 1) * PLN + 8 + 4 * t) = c1;
        *(float4*)(pl + (bi * 3 + 2) * PLN + 8 + 4 * t) = c2;
    }
    __syncthreads();

    if (t < 96) {                        // mirror halos: 6 rows x (8+8)
        int rb = t / 48, rem = t % 48;
        int c = rem >> 4, i = rem & 15;
        float* pp = pl + (rb * 3 + c) * PLN;
        if (i < 8) { int j = i + 1; pp[8 - j] = pp[8 + j]; }
        else { int r = i - 8; pp[1032 + r] = pp[1030 - r]; }
    }
    __syncthreads();

    float g[RAD + 1];
    g[0] = 1.7320508075688773f;
#pragma unroll
    for (int k = 1; k <= RAD; ++k) g[k] = g[k - 1] * (-0.26794919243112270647f);

    float res[2][3][4];
#pragma unroll
    for (int bi = 0; bi < 2; ++bi)
#pragma unroll
        for (int c = 0; c < 3; ++c) {
            const float* pp = pl + (bi * 3 + c) * PLN + 4 * t;
            float w[20];
#pragma unroll
            for (int i = 0; i < 5; ++i) {
                float4 v = *(const float4*)(pp + 4 * i);
                w[4 * i] = v.x; w[4 * i + 1] = v.y;
                w[4 * i + 2] = v.z; w[4 * i + 3] = v.w;
            }
#pragma unroll
            for (int j = 0; j < 4; ++j) {
                float a = g[0] * w[j + 8];
#pragma unroll
                for (int k = 1; k <= 8; ++k)
                    a += g[k] * (w[j + 8 - k] + w[j + 8 + k]);
                res[bi][c][j] = a;
            }
        }

#pragma unroll
    for (int c = 0; c < 3; ++c) {
        float4 o;
        o.x = pk2(res[0][c][0], res[1][c][0]);
        o.y = pk2(res[0][c][1], res[1][c][1]);
        o.z = pk2(res[0][c][2], res[1][c][2]);
        o.w = pk2(res[0][c][3], res[1][c][3]);
        *(float4*)(pairP + (size_t)(p * 3 + c) * HW_ + (size_t)h * W_ + 4 * t) = o;
    }
}

// ---------------- kernel 2: prefilter along H, pk-f16 math ----------------
// grid (32, 48): 48 identical pair-planes. 13-tap, v_pk_fma_f16.
#define TSTR 40
__global__ __launch_bounds__(256) void k_hfilt(float* __restrict__ pairP) {
    __shared__ float tile[H_ * TSTR];   // 40 KiB
    const int t = threadIdx.x;
    float* src = pairP + (size_t)blockIdx.y * HW_ + blockIdx.x * 32;

#pragma unroll
    for (int it = 0; it < 8; ++it) {
        int idx = t + it * 256;          // 0..2047 float4s
        int r = idx >> 3, seg = idx & 7;
        *(float4*)(tile + r * TSTR + seg * 4) =
            *(const float4*)(src + (size_t)r * W_ + seg * 4);
    }
    __syncthreads();

    float g[RADH + 1];
    g[0] = 1.7320508075688773f;
#pragma unroll
    for (int k = 1; k <= RADH; ++k) g[k] = g[k - 1] * (-0.26794919243112270647f);
    h2 gh[RADH + 1];
#pragma unroll
    for (int k = 0; k <= RADH; ++k) gh[k] = bch2(pk2(g[k], g[k]));

    const int cg = t & 7;
    const int prow = t >> 3;
    const int p0 = prow * 8;

    const h2 zz = bch2(0.f);
    h2 acc[8][4];
#pragma unroll
    for (int j = 0; j < 8; ++j)
#pragma unroll
        for (int q = 0; q < 4; ++q) acc[j][q] = zz;

#pragma unroll
    for (int r = 0; r < 8 + 2 * RADH; ++r) {   // 20 rows
        int hh = p0 - RADH + r;
        int m1 = hh < 0 ? -hh : hh;
        int m2 = 2 * (H_ - 1) - hh;
        int mp = m1 < m2 ? m1 : m2;
        float4 v = *(const float4*)(tile + mp * TSTR + cg * 4);
        h2 hv0 = bch2(v.x), hv1 = bch2(v.y), hv2 = bch2(v.z), hv3 = bch2(v.w);
#pragma unroll
        for (int j = 0; j < 8; ++j) {
            const int d = r - RADH - j;
            if (d >= -RADH && d <= RADH) {
                const h2 wgt = gh[d < 0 ? -d : d];
                acc[j][0] += wgt * hv0;
                acc[j][1] += wgt * hv1;
                acc[j][2] += wgt * hv2;
                acc[j][3] += wgt * hv3;
            }
        }
    }

#pragma unroll
    for (int j = 0; j < 8; ++j) {
        float4 o;
        o.x = bcf(acc[j][0]);
        o.y = bcf(acc[j][1]);
        o.z = bcf(acc[j][2]);
        o.w = bcf(acc[j][3]);
        *(float4*)(src + (size_t)(p0 + j) * W_ + cg * 4) = o;
    }
}

// ---------------- kernel 3: 4x4 cubic gather, batch-pair/thread -----------
// grid (1024, 16): thread owns (h,w) for batches (b0, b0+16).
__global__ __launch_bounds__(256) void k_sample(const float* __restrict__ pairP,
                                                const float2* __restrict__ dxy,
                                                float* __restrict__ out) {
    __shared__ float os[2][768];
    const int t = threadIdx.x;
    const int hw = blockIdx.x * 256 + t;
    const int b0 = blockIdx.y;            // 0..15; pair (b0, b0+16)
    const int h = hw >> 10, w = hw & 1023;

    float2 d = dxy[hw];
    float cy = (float)h + d.x;
    float cx = (float)w + d.y;
    float byf = floorf(cy), bxf = floorf(cx);
    int by = (int)byf, bx = (int)bxf;
    float wy[4], wx[4];
    cubw(cy - byf, wy);
    cubw(cx - bxf, wx);

    int iyW[4];
#pragma unroll
    for (int r = 0; r < 4; ++r)
        iyW[r] = min(max(by - 1 + r, 0), H_ - 1) * W_;

    const float* pc0 = pairP + (size_t)(b0 * 3) * HW_;
    const float* pc1 = pc0 + HW_;
    const float* pc2 = pc1 + HW_;

    float sA0 = 0.f, sA1 = 0.f, sA2 = 0.f;
    float sB0 = 0.f, sB1 = 0.f, sB2 = 0.f;

    if (bx >= 1 && bx <= W_ - 3) {
        const h2 w0 = bch2(pk2(wx[0], wx[0]));
        const h2 w1 = bch2(pk2(wx[1], wx[1]));
        const h2 w2 = bch2(pk2(wx[2], wx[2]));
        const h2 w3 = bch2(pk2(wx[3], wx[3]));

#pragma unroll
        for (int r = 0; r < 4; ++r) {
            const int o = iyW[r] + bx - 1;
            f4a v0 = *(const f4a*)(pc0 + o);
            f4a v1 = *(const f4a*)(pc1 + o);
            f4a v2 = *(const f4a*)(pc2 + o);
            const float wyr = wy[r];
            h2 a0 = bch2(v0.x) * w0 + bch2(v0.y) * w1;
            a0 = a0 + bch2(v0.z) * w2 + bch2(v0.w) * w3;
            h2 a1 = bch2(v1.x) * w0 + bch2(v1.y) * w1;
            a1 = a1 + bch2(v1.z) * w2 + bch2(v1.w) * w3;
            h2 a2 = bch2(v2.x) * w0 + bch2(v2.y) * w1;
            a2 = a2 + bch2(v2.z) * w2 + bch2(v2.w) * w3;
            float2 u0 = up2(bcf(a0));
            float2 u1 = up2(bcf(a1));
            float2 u2 = up2(bcf(a2));
            sA0 = fmaf(wyr, u0.x, sA0); sB0 = fmaf(wyr, u0.y, sB0);
            sA1 = fmaf(wyr, u1.x, sA1); sB1 = fmaf(wyr, u1.y, sB1);
            sA2 = fmaf(wyr, u2.x, sA2); sB2 = fmaf(wyr, u2.y, sB2);
        }
    } else {
        int ix4[4];
#pragma unroll
        for (int k = 0; k < 4; ++k) ix4[k] = min(max(bx - 1 + k, 0), W_ - 1);
#pragma unroll
        for (int r = 0; r < 4; ++r) {
            float wyr = wy[r];
#pragma unroll
            for (int k = 0; k < 4; ++k) {
                float wk = wyr * wx[k];
                int o = iyW[r] + ix4[k];
                float2 u0 = up2(pc0[o]);
                float2 u1 = up2(pc1[o]);
                float2 u2 = up2(pc2[o]);
                sA0 += wk * u0.x; sB0 += wk * u0.y;
                sA1 += wk * u1.x; sB1 += wk * u1.y;
                sA2 += wk * u2.x; sB2 += wk * u2.y;
            }
        }
    }

    os[0][3 * t + 0] = clamp01(sA0);
    os[0][3 * t + 1] = clamp01(sA1);
    os[0][3 * t + 2] = clamp01(sA2);
    os[1][3 * t + 0] = clamp01(sB0);
    os[1][3 * t + 1] = clamp01(sB1);
    os[1][3 * t + 2] = clamp01(sB2);
    __syncthreads();

    if (t < 192) {
        float4 vA = *(const float4*)(&os[0][0] + 4 * t);
        float4 vB = *(const float4*)(&os[1][0] + 4 * t);
        float* oA = out + ((size_t)b0 * HW_ + (size_t)blockIdx.x * 256) * 3;
        float* oB = out + ((size_t)(b0 + 16) * HW_ + (size_t)blockIdx.x * 256) * 3;
        *(float4*)(oA + 4 * t) = vA;
        *(float4*)(oB + 4 * t) = vB;
    }
}

extern "C" void kernel_launch(void* const* d_in, const int* in_sizes, int n_in,
                              void* d_out, int out_size, void* d_ws, size_t ws_size,
                              hipStream_t stream) {
    const float* x = (const float*)d_in[0];      // [32,256,1024,3]
    const float* disp = (const float*)d_in[1];   // [2,3,3]
    float* out = (float*)d_out;

    char* ws = (char*)d_ws;
    float* pairP = (float*)ws;                     // 48 MiB: 48 pair-planes
    float2* dxy = (float2*)(ws + 50331648ull);     // 2 MiB

    k_disp<<<dim3(HW_ / 256), dim3(256), 0, stream>>>(disp, dxy);

    k_wfilt<<<dim3((B_ / 2) * H_), dim3(256), 0, stream>>>(x, pairP);

    k_hfilt<<<dim3(32, 48), dim3(256), 0, stream>>>(pairP);

    k_sample<<<dim3(HW_ / 256, B_ / 2), dim3(256), 0, stream>>>(pairP, dxy, out);
}